// Round 16
// baseline (1330.112 us; speedup 1.0000x reference)
//
#include <hip/hip_runtime.h>

#define T_TOK 8192   // B*S tokens
#define HDIM  2048
#define IDIM  8192
#define KKEEP 4096
#define TCHK  4096   // token chunk for UP (U parks in d_out, 67 MB)
#define BAND  1.6e-3f
#define MAXB  192

typedef _Float16 f16x8 __attribute__((ext_vector_type(8)));
typedef float    f32x4 __attribute__((ext_vector_type(4)));
typedef ushort   u16x8 __attribute__((ext_vector_type(8)));

#define AS1 __attribute__((address_space(1)))
#define AS3 __attribute__((address_space(3)))
#define BARR asm volatile("s_barrier" ::: "memory")

// LDS permutation for 64-B rows (BK=32): bits[4:5] ^= bits[7:8], bit[6] ^= bit[8].
__device__ __forceinline__ int swzA(int b) {
    return b ^ ((b >> 3) & 0x30) ^ ((b >> 2) & 0x40);
}

union H16 { ushort u; _Float16 h; };

// ---------------- cast ----------------

__global__ void cast_f16(const float4* __restrict__ in, ushort4* __restrict__ o, long n4) {
    long stride = (long)gridDim.x * blockDim.x;
    for (long i = (long)blockIdx.x * blockDim.x + threadIdx.x; i < n4; i += stride) {
        float4 v = in[i];
        float vv[4] = {v.x, v.y, v.z, v.w};
        union { _Float16 f[4]; ushort4 u; } H;
        #pragma unroll
        for (int j = 0; j < 4; ++j) H.f[j] = (_Float16)vv[j];
        o[i] = H.u;
    }
}

#define GLOAD(src_, dst_) \
    __builtin_amdgcn_global_load_lds((const AS1 void*)(src_), (AS3 void*)(dst_), 16, 0, 0)

// ------- 256x128 GEMM, BK=32, 2-buf LDS, 4 waves, 2 independent blocks/CU -------
// MODE 0: f32 out (DOWN)   MODE 1: f16 out (GATE, UP)
// Per tile: A 16KB + B 8KB = 24KB; 2 bufs = 48KB LDS -> 2 blocks/CU (96KB).
// Regs: acc 128 + frags 48 + addr ~15 ~= 191 < 256 cap (launch_bounds(256,2)).

#define STAGE6(pA_, pB_, kt_, buf_) do { \
    char* db_ = Lc + (buf_)*24576 + wave*1024; \
    GLOAD((pA_) + aBase + (kt_) + oA0, db_); \
    GLOAD((pA_) + aBase + (kt_) + oA1, db_ +  4096); \
    GLOAD((pA_) + aBase + (kt_) + oA2, db_ +  8192); \
    GLOAD((pA_) + aBase + (kt_) + oA3, db_ + 12288); \
    GLOAD((pB_) + bBase + (kt_) + oB0, db_ + 16384); \
    GLOAD((pB_) + bBase + (kt_) + oB1, db_ + 20480); \
  } while (0)

template <int MODE>
__global__ __launch_bounds__(256, 2) void gemm3(
    const _Float16* __restrict__ A0, const _Float16* __restrict__ B0,
    int N, int Kp, float* __restrict__ Cf, _Float16* __restrict__ Ch)
{
    __shared__ __align__(128) char Lc[49152];    // 2 bufs x 24 KB (A 16K | B 8K)
    const int tid  = threadIdx.x;
    const int lane = tid & 63;
    const int wave = tid >> 6;                   // 4 waves
    const int wr = wave >> 1, wc = wave & 1;     // wave tile 128x64

    // XCD-bijective block swizzle
    const int gx = gridDim.x, gy = gridDim.y;
    const int nwg = gx * gy;
    const int orig = blockIdx.y * gx + blockIdx.x;
    const int q = nwg >> 3, r = nwg & 7, xcd = orig & 7, lid = orig >> 3;
    const int wg = (xcd < r ? xcd * (q + 1) : r * (q + 1) + (xcd - r) * q) + lid;
    const int bm = wg / gy, bn = wg % gy;

    // staging map: linear LDS dest (tid*16 per 4KB sweep) <- inverse-swizzled src
    int oA0, oA1, oA2, oA3, oB0, oB1;
    {
        int o[6];
        #pragma unroll
        for (int g = 0; g < 6; ++g) {
            int p = (g < 4 ? g : g - 4) * 4096 + tid * 16;  // pos within A- or B-half
            int l = swzA(p);
            int row = l >> 6;                    // A: 0..255, B: 0..127
            int col = (l & 63) >> 1;
            o[g] = row * Kp + col;
        }
        oA0 = o[0]; oA1 = o[1]; oA2 = o[2]; oA3 = o[3]; oB0 = o[4]; oB1 = o[5];
    }
    const size_t aBase = (size_t)bm * 256 * Kp;
    const size_t bBase = (size_t)bn * 128 * Kp;

    const int l15 = lane & 15, lhi = lane >> 4;
    const int pa = swzA((wr * 128 + l15) * 64 + lhi * 16);           // A half (0)
    const int pb = 16384 + swzA((wc * 64 + l15) * 64 + lhi * 16);    // B half

    const int NT = Kp >> 5;
    f32x4 acc[8][4] = {};

    STAGE6(A0, B0, 0,  0);
    STAGE6(A0, B0, 32, 1);

    for (int t = 0; t < NT; ++t) {
        if (t + 1 < NT) asm volatile("s_waitcnt vmcnt(6)" ::: "memory");
        else            asm volatile("s_waitcnt vmcnt(0)" ::: "memory");
        BARR;                                    // tile t published

        const char* bp = Lc + (t & 1) * 24576;
        f16x8 af[8], bfv[4];
        #pragma unroll
        for (int m = 0; m < 8; ++m) af[m]  = *(const f16x8*)(bp + pa + m * 1024);
        #pragma unroll
        for (int n = 0; n < 4; ++n) bfv[n] = *(const f16x8*)(bp + pb + n * 1024);

        asm volatile("s_waitcnt lgkmcnt(0)" ::: "memory");   // own reads done
        BARR;                                                // all reads done (WAR)

        if (t + 2 < NT) STAGE6(A0, B0, (t + 2) << 5, t & 1);

        __builtin_amdgcn_sched_barrier(0);
        __builtin_amdgcn_s_setprio(1);
        #pragma unroll
        for (int m = 0; m < 8; ++m)
            #pragma unroll
            for (int n = 0; n < 4; ++n)
                acc[m][n] = __builtin_amdgcn_mfma_f32_16x16x32_f16(af[m], bfv[n], acc[m][n], 0, 0, 0);
        __builtin_amdgcn_s_setprio(0);
    }

    // epilogue; C/D layout: col = lane&15, row = (lane>>4)*4 + reg
    const int r0 = bm * 256 + wr * 128 + (lane >> 4) * 4;
    const int c0 = bn * 128 + wc * 64 + (lane & 15);
    #pragma unroll
    for (int m = 0; m < 8; ++m) {
        #pragma unroll
        for (int n = 0; n < 4; ++n) {
            #pragma unroll
            for (int rr = 0; rr < 4; ++rr) {
                const size_t idx = (size_t)(r0 + m * 16 + rr) * N + (c0 + n * 16);
                if (MODE == 0) Cf[idx] = acc[m][n][rr];
                else           Ch[idx] = (_Float16)acc[m][n][rr];
            }
        }
    }
}

// ---- topk + exact band-recompute + fused P = mask * g * u — VECTORIZED ----

__global__ __launch_bounds__(256) void topk_sel(
    _Float16* __restrict__ GP, const _Float16* __restrict__ U,
    const float* __restrict__ xf, const float* __restrict__ Wgf)
{
    __shared__ ushort keys[IDIM];
    __shared__ float  xrow[HDIM];
    __shared__ unsigned char bmap[IDIM];
    __shared__ unsigned hist[256], sA_[256], sB_[256];
    __shared__ unsigned selBin, selAbove;
    __shared__ int Acnt, nbv;
    __shared__ int   bidxs[MAXB];
    __shared__ float bval[MAXB];
    __shared__ int   kflag[MAXB];

    const int tid = threadIdx.x;
    const int t = blockIdx.x;
    _Float16* grow = GP + (size_t)t * IDIM;
    const _Float16* urow = U + (size_t)t * IDIM;

    if (tid == 0) { Acnt = 0; nbv = 0; }
    for (int j8 = tid * 8; j8 < IDIM; j8 += 2048) {
        u16x8 v = *(const u16x8*)(grow + j8);
        u16x8 k;
        #pragma unroll
        for (int e = 0; e < 8; ++e) k[e] = (ushort)(v[e] & 0x7FFFu);
        *(u16x8*)(keys + j8) = k;
    }
    for (int j4 = tid; j4 < IDIM / 4; j4 += 256)
        ((unsigned*)bmap)[j4] = 0xFFFFFFFFu;
    for (int j4 = tid * 4; j4 < HDIM; j4 += 1024)
        *(float4*)(xrow + j4) = *(const float4*)(xf + (size_t)t * HDIM + j4);
    __syncthreads();

    unsigned kq = 0;
    int Krem = KKEEP;
    for (int pass = 0; pass < 2; ++pass) {
        const int shift = pass == 0 ? 7 : 0;
        const unsigned msk = pass == 0 ? 255u : 127u;
        hist[tid] = 0;
        __syncthreads();
        for (int j8 = tid * 8; j8 < IDIM; j8 += 2048) {
            u16x8 kv = *(const u16x8*)(keys + j8);
            #pragma unroll
            for (int e = 0; e < 8; ++e) {
                unsigned k = kv[e];
                bool ok = (pass == 0) || ((k >> 7) == (kq >> 7));
                if (ok) atomicAdd(&hist[(k >> shift) & msk], 1u);
            }
        }
        __syncthreads();
        sA_[tid] = hist[tid];
        __syncthreads();
        unsigned *src = sA_, *dst = sB_;
        for (int off = 1; off < 256; off <<= 1) {
            unsigned v = src[tid] + ((tid + off < 256) ? src[tid + off] : 0u);
            dst[tid] = v;
            __syncthreads();
            unsigned* tmp = src; src = dst; dst = tmp;
        }
        unsigned S  = src[tid];
        unsigned Sn = (tid < 255) ? src[tid + 1] : 0u;
        if ((int)S >= Krem && (int)Sn < Krem) { selBin = (unsigned)tid; selAbove = Sn; }
        __syncthreads();
        kq |= selBin << shift;
        Krem -= (int)selAbove;
        __syncthreads();
    }
    H16 cv; cv.u = (ushort)kq;
    const float kthf = (float)cv.h;
    const float hif = kthf + BAND;
    const float lof = kthf - BAND;

    for (int j8 = tid * 8; j8 < IDIM; j8 += 2048) {
        u16x8 kv = *(const u16x8*)(keys + j8);
        #pragma unroll
        for (int e = 0; e < 8; ++e) {
            H16 c; c.u = kv[e];
            float v = (float)c.h;
            if (v > hif) atomicAdd(&Acnt, 1);
            else if (v >= lof) {
                int s = atomicAdd(&nbv, 1);
                if (s < MAXB) { bidxs[s] = j8 + e; bmap[j8 + e] = (unsigned char)s; }
            }
        }
    }
    __syncthreads();

    const int nbc = nbv < MAXB ? nbv : MAXB;
    int R = KKEEP - Acnt;
    R = R < 0 ? 0 : (R > nbc ? nbc : R);

    const int wv = tid >> 6, ln = tid & 63;
    for (int j = wv; j < nbc; j += 4) {
        const float* wrow = Wgf + (size_t)bidxs[j] * HDIM;
        float s = 0.f;
        #pragma unroll
        for (int it = 0; it < HDIM / 256; ++it) {
            const int c = it * 256 + ln * 4;
            float4 w = *(const float4*)(wrow + c);
            float4 xv = *(const float4*)(xrow + c);
            s = fmaf(xv.x, w.x, s);
            s = fmaf(xv.y, w.y, s);
            s = fmaf(xv.z, w.z, s);
            s = fmaf(xv.w, w.w, s);
        }
        #pragma unroll
        for (int o = 32; o; o >>= 1) s += __shfl_xor(s, o);
        if (ln == 0) bval[j] = fabsf(s);
    }
    __syncthreads();

    for (int j = tid; j < nbc; j += 256) {
        int rk = 0;
        float vj = bval[j];
        for (int k = 0; k < nbc; ++k) rk += (bval[k] > vj);
        kflag[j] = (rk < R) ? 1 : 0;
    }
    __syncthreads();

    for (int j8 = tid * 8; j8 < IDIM; j8 += 2048) {
        u16x8 g8 = *(const u16x8*)(grow + j8);
        u16x8 u8 = *(const u16x8*)(urow + j8);
        u16x8 p8;
        #pragma unroll
        for (int e = 0; e < 8; ++e) {
            H16 cg; cg.u = g8[e];
            H16 cu; cu.u = u8[e];
            float g = (float)cg.h;
            float v = fabsf(g);
            bool keep;
            unsigned char s = bmap[j8 + e];
            if (s != 255)      keep = (kflag[s] != 0);
            else if (v > hif)  keep = true;
            else if (v < lof)  keep = false;
            else               keep = (v >= kthf);
            H16 cp; cp.h = keep ? (_Float16)(g * (float)cu.h) : (_Float16)0.f;
            p8[e] = cp.u;
        }
        *(u16x8*)(grow + j8) = p8;
    }
}

// ---------------- host ----------------

extern "C" void kernel_launch(void* const* d_in, const int* in_sizes, int n_in,
                              void* d_out, int out_size, void* d_ws, size_t ws_size,
                              hipStream_t stream) {
    const float* x  = (const float*)d_in[0];   // [T,H]
    const float* Wg = (const float*)d_in[1];   // [I,H]
    const float* Wu = (const float*)d_in[2];   // [I,H]
    const float* Wd = (const float*)d_in[3];   // [H,I]

    const size_t NE   = (size_t)T_TOK * HDIM;
    const size_t szH2 = NE * 2;

    char* ws = (char*)d_ws;
    _Float16* xh   = (_Float16*)ws;
    _Float16* Wgh  = (_Float16*)(ws + szH2);
    _Float16* Wu16 = (_Float16*)(ws + 2 * szH2);
    _Float16* Wd16 = (_Float16*)(ws + 3 * szH2);
    _Float16* G    = (_Float16*)(ws + 4 * szH2);   // [T][I] f16 gate -> P in place
    _Float16* Uc   = (_Float16*)d_out;             // per-chunk U

    const long n4 = (long)(NE / 4);
    cast_f16<<<1024, 256, 0, stream>>>((const float4*)x,  (ushort4*)xh,   n4);
    cast_f16<<<1024, 256, 0, stream>>>((const float4*)Wg, (ushort4*)Wgh,  n4);
    cast_f16<<<1024, 256, 0, stream>>>((const float4*)Wu, (ushort4*)Wu16, n4);
    cast_f16<<<1024, 256, 0, stream>>>((const float4*)Wd, (ushort4*)Wd16, n4);

    // GATE: full-size 1-pass f16 gate
    gemm3<1><<<dim3(T_TOK / 256, IDIM / 128), 256, 0, stream>>>(
        xh, Wgh, IDIM, HDIM, nullptr, G);

    for (int c0 = 0; c0 < T_TOK; c0 += TCHK) {
        gemm3<1><<<dim3(TCHK / 256, IDIM / 128), 256, 0, stream>>>(
            xh + (size_t)c0 * HDIM, Wu16, IDIM, HDIM, nullptr, Uc);
        topk_sel<<<TCHK, 256, 0, stream>>>(
            G + (size_t)c0 * IDIM, Uc, x + (size_t)c0 * HDIM, Wg);
    }

    // DOWN: out = P @ Wd^T
    gemm3<0><<<dim3(T_TOK / 256, HDIM / 128), 256, 0, stream>>>(
        G, Wd16, HDIM, IDIM, (float*)d_out, nullptr);
}

// Round 17
// 1286.898 us; speedup vs baseline: 1.0336x; 1.0336x over previous
//
#include <hip/hip_runtime.h>

#define T_TOK 8192   // B*S tokens
#define HDIM  2048
#define IDIM  8192
#define KKEEP 4096
#define TCHK  4096   // token chunk for UP (U parks in d_out, 67 MB)
#define BAND  1.6e-3f
#define MAXB  192

typedef _Float16 f16x8 __attribute__((ext_vector_type(8)));
typedef float    f32x4 __attribute__((ext_vector_type(4)));
typedef ushort   u16x8 __attribute__((ext_vector_type(8)));

#define AS1 __attribute__((address_space(1)))
#define AS3 __attribute__((address_space(3)))
#define BARR asm volatile("s_barrier" ::: "memory")

// LDS permutation for 64-B rows (BK=32): bits[4:5] ^= bits[7:8], bit[6] ^= bit[8].
__device__ __forceinline__ int swzA(int b) {
    return b ^ ((b >> 3) & 0x30) ^ ((b >> 2) & 0x40);
}

union H16 { ushort u; _Float16 h; };

// ---------------- merged cast (grid.y = array index) ----------------

__global__ void cast_all(const float4* __restrict__ x,  const float4* __restrict__ wg,
                         const float4* __restrict__ wu, const float4* __restrict__ wd,
                         ushort4* __restrict__ xo,  ushort4* __restrict__ wgo,
                         ushort4* __restrict__ wuo, ushort4* __restrict__ wdo, long n4) {
    const float4* in; ushort4* out;
    switch (blockIdx.y) {
        case 0:  in = x;  out = xo;  break;
        case 1:  in = wg; out = wgo; break;
        case 2:  in = wu; out = wuo; break;
        default: in = wd; out = wdo; break;
    }
    long stride = (long)gridDim.x * blockDim.x;
    for (long i = (long)blockIdx.x * blockDim.x + threadIdx.x; i < n4; i += stride) {
        float4 v = in[i];
        float vv[4] = {v.x, v.y, v.z, v.w};
        union { _Float16 f[4]; ushort4 u; } H;
        #pragma unroll
        for (int j = 0; j < 4; ++j) H.f[j] = (_Float16)vv[j];
        out[i] = H.u;
    }
}

#define GLOAD(src_, dst_) \
    __builtin_amdgcn_global_load_lds((const AS1 void*)(src_), (AS3 void*)(dst_), 16, 0, 0)

// ------- 256x256 GEMM, BK=32, 4-deep LDS pipeline + 1-deep fragment dbuf -------
// MODE 0: f32 out (DOWN)   MODE 1: f16 out (GATE, UP) with LDS-transposed epilogue

#define STAGE4(pA_, pB_, kt_, buf_) do { \
    char* db_ = Lc + (buf_)*32768 + wave*1024; \
    GLOAD((pA_) + aBase + (kt_) + off0, db_); \
    GLOAD((pA_) + aBase + (kt_) + off1, db_ +  8192); \
    GLOAD((pB_) + bBase + (kt_) + off2, db_ + 16384); \
    GLOAD((pB_) + bBase + (kt_) + off3, db_ + 24576); \
  } while (0)

#define RDFRAG(dstA_, dstB_, tt_) do { \
    const char* bp_ = Lc + ((tt_) & 3) * 32768; \
    _Pragma("unroll") \
    for (int m_ = 0; m_ < 8; ++m_) (dstA_)[m_] = *(const f16x8*)(bp_ + pa + m_ * 1024); \
    _Pragma("unroll") \
    for (int n_ = 0; n_ < 4; ++n_) (dstB_)[n_] = *(const f16x8*)(bp_ + pb + n_ * 1024); \
  } while (0)

// iter body: gate+publish, stage t+3, prefetch-read frags(t+1)->NXT, MFMA(t) on CUR
#define BODY(t_, curA_, curB_, nxtA_, nxtB_) do { \
    if ((t_) + 2 < NT) asm volatile("s_waitcnt vmcnt(4)" ::: "memory"); \
    else               asm volatile("s_waitcnt vmcnt(0)" ::: "memory"); \
    BARR; \
    if ((t_) + 3 < NT) STAGE4(A0, B0, ((t_) + 3) << 5, ((t_) + 3) & 3); \
    if ((t_) + 1 < NT) RDFRAG(nxtA_, nxtB_, (t_) + 1); \
    __builtin_amdgcn_s_setprio(1); \
    _Pragma("unroll") \
    for (int m_ = 0; m_ < 8; ++m_) \
      _Pragma("unroll") \
      for (int n_ = 0; n_ < 4; ++n_) \
        acc[m_][n_] = __builtin_amdgcn_mfma_f32_16x16x32_f16((curA_)[m_], (curB_)[n_], acc[m_][n_], 0, 0, 0); \
    __builtin_amdgcn_s_setprio(0); \
  } while (0)

template <int MODE>
__global__ __launch_bounds__(512, 2) void gemm4(
    const _Float16* __restrict__ A0, const _Float16* __restrict__ B0,
    int N, int Kp, float* __restrict__ Cf, _Float16* __restrict__ Ch)
{
    __shared__ __align__(128) char Lc[131072];   // 4 bufs x 32 KB (A 16K | B 16K)
    const int tid  = threadIdx.x;
    const int lane = tid & 63;
    const int wave = tid >> 6;
    const int wr = wave >> 2, wc = wave & 3;     // wave tile 128x64

    // XCD-bijective block swizzle
    const int gx = gridDim.x, gy = gridDim.y;
    const int nwg = gx * gy;
    const int orig = blockIdx.y * gx + blockIdx.x;
    const int q = nwg >> 3, r = nwg & 7, xcd = orig & 7, lid = orig >> 3;
    const int wg = (xcd < r ? xcd * (q + 1) : r * (q + 1) + (xcd - r) * q) + lid;
    const int bm = wg / gy, bn = wg % gy;

    // staging map: linear LDS dest (tid*16) <- inverse-swizzled global source
    int off0, off1, off2, off3;
    {
        int o[4];
        #pragma unroll
        for (int g = 0; g < 4; ++g) {
            int p = g * 8192 + tid * 16;
            int l = swzA(p);
            int row = (l >> 6) & 255;
            int col = (l & 63) >> 1;
            o[g] = row * Kp + col;
        }
        off0 = o[0]; off1 = o[1]; off2 = o[2]; off3 = o[3];
    }
    const size_t aBase = (size_t)bm * 256 * Kp;
    const size_t bBase = (size_t)bn * 256 * Kp;

    const int l15 = lane & 15, lhi = lane >> 4;
    const int pa = swzA((wr * 128 + l15) * 64 + lhi * 16);
    const int pb = swzA(16384 + (wc * 64 + l15) * 64 + lhi * 16);

    const int NT = Kp >> 5;                       // even for all our shapes
    f32x4 acc[8][4] = {};
    f16x8 a0f[8], b0f[4], a1f[8], b1f[4];

    STAGE4(A0, B0, 0,  0);
    STAGE4(A0, B0, 32, 1);
    STAGE4(A0, B0, 64, 2);
    asm volatile("s_waitcnt vmcnt(8)" ::: "memory");
    BARR;
    RDFRAG(a0f, b0f, 0);

    for (int t = 0; t < NT; t += 2) {
        BODY(t,     a0f, b0f, a1f, b1f);
        BODY(t + 1, a1f, b1f, a0f, b0f);
    }

    // epilogue; acc layout: col = lane&15, row = (lane>>4)*4 + reg
    if (MODE == 0) {
        const int r0 = bm * 256 + wr * 128 + (lane >> 4) * 4;
        const int c0 = bn * 256 + wc * 64 + (lane & 15);
        #pragma unroll
        for (int m = 0; m < 8; ++m)
            #pragma unroll
            for (int n = 0; n < 4; ++n)
                #pragma unroll
                for (int rr = 0; rr < 4; ++rr)
                    Cf[(size_t)(r0 + m * 16 + rr) * N + (c0 + n * 16)] = acc[m][n][rr];
    } else {
        // f16 out: per-wave LDS transpose -> fully coalesced 16B stores
        BARR;                                    // all waves done reading K-loop LDS
        char* ep = Lc + wave * 16384;            // 128 rows x 128 B (64 f16 cols)
        #pragma unroll
        for (int m = 0; m < 8; ++m) {
            #pragma unroll
            for (int n = 0; n < 4; ++n) {
                #pragma unroll
                for (int rr = 0; rr < 4; ++rr) {
                    const int row = m * 16 + (lane >> 4) * 4 + rr;
                    const int col = n * 16 + (lane & 15);
                    const int bo = (row * 128 + col * 2) ^ ((row & 7) << 4);
                    *(_Float16*)(ep + bo) = (_Float16)acc[m][n][rr];
                }
            }
        }
        asm volatile("s_waitcnt lgkmcnt(0)" ::: "memory");
        const int rg0 = bm * 256 + wr * 128;
        const int cg0 = bn * 256 + wc * 64 + (lane & 7) * 8;
        #pragma unroll
        for (int it = 0; it < 16; ++it) {
            const int row = it * 8 + (lane >> 3);
            const int bo = (row * 128 + (lane & 7) * 16) ^ ((row & 7) << 4);
            f16x8 v = *(const f16x8*)(ep + bo);
            *(f16x8*)(Ch + (size_t)(rg0 + row) * N + cg0) = v;
        }
    }
}

// ---- topk + exact band-recompute + fused P = mask * g * u — VECTORIZED ----

__global__ __launch_bounds__(256) void topk_sel(
    _Float16* __restrict__ GP, const _Float16* __restrict__ U,
    const float* __restrict__ xf, const float* __restrict__ Wgf)
{
    __shared__ ushort keys[IDIM];
    __shared__ float  xrow[HDIM];
    __shared__ unsigned char bmap[IDIM];
    __shared__ unsigned hw[4][256];
    __shared__ unsigned hist[256], sA_[256], sB_[256];
    __shared__ unsigned selBin, selAbove;
    __shared__ int Acnt, nbv;
    __shared__ int   bidxs[MAXB];
    __shared__ float bval[MAXB];
    __shared__ int   kflag[MAXB];

    const int tid = threadIdx.x;
    const int wv = tid >> 6, ln = tid & 63;
    const int t = blockIdx.x;
    _Float16* grow = GP + (size_t)t * IDIM;
    const _Float16* urow = U + (size_t)t * IDIM;

    if (tid == 0) { Acnt = 0; nbv = 0; }
    for (int j8 = tid * 8; j8 < IDIM; j8 += 2048) {
        u16x8 v = *(const u16x8*)(grow + j8);
        u16x8 k;
        #pragma unroll
        for (int e = 0; e < 8; ++e) k[e] = (ushort)(v[e] & 0x7FFFu);
        *(u16x8*)(keys + j8) = k;
    }
    for (int j4 = tid; j4 < IDIM / 4; j4 += 256)
        ((unsigned*)bmap)[j4] = 0xFFFFFFFFu;
    for (int j4 = tid * 4; j4 < HDIM; j4 += 1024)
        *(float4*)(xrow + j4) = *(const float4*)(xf + (size_t)t * HDIM + j4);
    #pragma unroll
    for (int b = ln; b < 256; b += 64) hw[wv][b] = 0;
    __syncthreads();

    // pass 0: per-wave histograms (top byte), then reduce
    for (int j8 = tid * 8; j8 < IDIM; j8 += 2048) {
        u16x8 kv = *(const u16x8*)(keys + j8);
        #pragma unroll
        for (int e = 0; e < 8; ++e)
            atomicAdd(&hw[wv][(kv[e] >> 7) & 255u], 1u);
    }
    __syncthreads();
    hist[tid] = hw[0][tid] + hw[1][tid] + hw[2][tid] + hw[3][tid];
    __syncthreads();

    unsigned kq = 0;
    int Krem = KKEEP;
    for (int pass = 0; pass < 2; ++pass) {
        const int shift = pass == 0 ? 7 : 0;
        if (pass == 1) {
            hist[tid] = 0;
            __syncthreads();
            for (int j8 = tid * 8; j8 < IDIM; j8 += 2048) {
                u16x8 kv = *(const u16x8*)(keys + j8);
                #pragma unroll
                for (int e = 0; e < 8; ++e) {
                    unsigned k = kv[e];
                    if ((k >> 7) == (kq >> 7)) atomicAdd(&hist[k & 127u], 1u);
                }
            }
            __syncthreads();
        }
        sA_[tid] = hist[tid];
        __syncthreads();
        unsigned *src = sA_, *dst = sB_;
        for (int off = 1; off < 256; off <<= 1) {
            unsigned v = src[tid] + ((tid + off < 256) ? src[tid + off] : 0u);
            dst[tid] = v;
            __syncthreads();
            unsigned* tmp = src; src = dst; dst = tmp;
        }
        unsigned S  = src[tid];
        unsigned Sn = (tid < 255) ? src[tid + 1] : 0u;
        if ((int)S >= Krem && (int)Sn < Krem) { selBin = (unsigned)tid; selAbove = Sn; }
        __syncthreads();
        kq |= selBin << shift;
        Krem -= (int)selAbove;
        __syncthreads();
    }
    H16 cv; cv.u = (ushort)kq;
    const float kthf = (float)cv.h;
    const float hif = kthf + BAND;
    const float lof = kthf - BAND;

    for (int j8 = tid * 8; j8 < IDIM; j8 += 2048) {
        u16x8 kv = *(const u16x8*)(keys + j8);
        #pragma unroll
        for (int e = 0; e < 8; ++e) {
            H16 c; c.u = kv[e];
            float v = (float)c.h;
            if (v > hif) atomicAdd(&Acnt, 1);
            else if (v >= lof) {
                int s = atomicAdd(&nbv, 1);
                if (s < MAXB) { bidxs[s] = j8 + e; bmap[j8 + e] = (unsigned char)s; }
            }
        }
    }
    __syncthreads();

    const int nbc = nbv < MAXB ? nbv : MAXB;
    int R = KKEEP - Acnt;
    R = R < 0 ? 0 : (R > nbc ? nbc : R);

    for (int j = wv; j < nbc; j += 4) {
        const float* wrow = Wgf + (size_t)bidxs[j] * HDIM;
        float s = 0.f;
        #pragma unroll
        for (int it = 0; it < HDIM / 256; ++it) {
            const int c = it * 256 + ln * 4;
            float4 w = *(const float4*)(wrow + c);
            float4 xv = *(const float4*)(xrow + c);
            s = fmaf(xv.x, w.x, s);
            s = fmaf(xv.y, w.y, s);
            s = fmaf(xv.z, w.z, s);
            s = fmaf(xv.w, w.w, s);
        }
        #pragma unroll
        for (int o = 32; o; o >>= 1) s += __shfl_xor(s, o);
        if (ln == 0) bval[j] = fabsf(s);
    }
    __syncthreads();

    for (int j = tid; j < nbc; j += 256) {
        int rk = 0;
        float vj = bval[j];
        for (int k = 0; k < nbc; ++k) rk += (bval[k] > vj);
        kflag[j] = (rk < R) ? 1 : 0;
    }
    __syncthreads();

    for (int j8 = tid * 8; j8 < IDIM; j8 += 2048) {
        u16x8 g8 = *(const u16x8*)(grow + j8);
        u16x8 u8 = *(const u16x8*)(urow + j8);
        u16x8 p8;
        #pragma unroll
        for (int e = 0; e < 8; ++e) {
            H16 cg; cg.u = g8[e];
            H16 cu; cu.u = u8[e];
            float g = (float)cg.h;
            float v = fabsf(g);
            bool keep;
            unsigned char s = bmap[j8 + e];
            if (s != 255)      keep = (kflag[s] != 0);
            else if (v > hif)  keep = true;
            else if (v < lof)  keep = false;
            else               keep = (v >= kthf);
            H16 cp; cp.h = keep ? (_Float16)(g * (float)cu.h) : (_Float16)0.f;
            p8[e] = cp.u;
        }
        *(u16x8*)(grow + j8) = p8;
    }
}

// ---------------- host ----------------

extern "C" void kernel_launch(void* const* d_in, const int* in_sizes, int n_in,
                              void* d_out, int out_size, void* d_ws, size_t ws_size,
                              hipStream_t stream) {
    const float* x  = (const float*)d_in[0];   // [T,H]
    const float* Wg = (const float*)d_in[1];   // [I,H]
    const float* Wu = (const float*)d_in[2];   // [I,H]
    const float* Wd = (const float*)d_in[3];   // [H,I]

    const size_t NE   = (size_t)T_TOK * HDIM;
    const size_t szH2 = NE * 2;

    char* ws = (char*)d_ws;
    _Float16* xh   = (_Float16*)ws;
    _Float16* Wgh  = (_Float16*)(ws + szH2);
    _Float16* Wu16 = (_Float16*)(ws + 2 * szH2);
    _Float16* Wd16 = (_Float16*)(ws + 3 * szH2);
    _Float16* G    = (_Float16*)(ws + 4 * szH2);   // [T][I] f16 gate -> P in place
    _Float16* Uc   = (_Float16*)d_out;             // per-chunk U

    const long n4 = (long)(NE / 4);
    cast_all<<<dim3(512, 4), 256, 0, stream>>>(
        (const float4*)x, (const float4*)Wg, (const float4*)Wu, (const float4*)Wd,
        (ushort4*)xh, (ushort4*)Wgh, (ushort4*)Wu16, (ushort4*)Wd16, n4);

    // GATE: full-size 1-pass f16 gate
    gemm4<1><<<dim3(T_TOK / 256, IDIM / 256), 512, 0, stream>>>(
        xh, Wgh, IDIM, HDIM, nullptr, G);

    for (int c0 = 0; c0 < T_TOK; c0 += TCHK) {
        gemm4<1><<<dim3(TCHK / 256, IDIM / 256), 512, 0, stream>>>(
            xh + (size_t)c0 * HDIM, Wu16, IDIM, HDIM, nullptr, Uc);
        topk_sel<<<TCHK, 256, 0, stream>>>(
            G + (size_t)c0 * IDIM, Uc, x + (size_t)c0 * HDIM, Wg);
    }

    // DOWN: out = P @ Wd^T
    gemm4<0><<<dim3(T_TOK / 256, HDIM / 256), 512, 0, stream>>>(
        G, Wd16, HDIM, IDIM, (float*)d_out, nullptr);
}

// Round 18
// 1225.351 us; speedup vs baseline: 1.0855x; 1.0502x over previous
//
#include <hip/hip_runtime.h>

#define T_TOK 8192   // B*S tokens
#define HDIM  2048
#define IDIM  8192
#define KKEEP 4096
#define TCHK  4096   // token chunk for UP (U parks in d_out, 67 MB)
#define BAND  1.6e-3f
#define MAXB  192

typedef _Float16 f16x8 __attribute__((ext_vector_type(8)));
typedef float    f32x4 __attribute__((ext_vector_type(4)));
typedef ushort   u16x8 __attribute__((ext_vector_type(8)));

#define AS1 __attribute__((address_space(1)))
#define AS3 __attribute__((address_space(3)))
#define BARR asm volatile("s_barrier" ::: "memory")

// LDS permutation for 64-B rows (BK=32): bits[4:5] ^= bits[7:8], bit[6] ^= bit[8].
__device__ __forceinline__ int swzA(int b) {
    return b ^ ((b >> 3) & 0x30) ^ ((b >> 2) & 0x40);
}

union H16 { ushort u; _Float16 h; };

// ---------------- cast ----------------

__global__ void cast_f16(const float4* __restrict__ in, ushort4* __restrict__ o, long n4) {
    long stride = (long)gridDim.x * blockDim.x;
    for (long i = (long)blockIdx.x * blockDim.x + threadIdx.x; i < n4; i += stride) {
        float4 v = in[i];
        float vv[4] = {v.x, v.y, v.z, v.w};
        union { _Float16 f[4]; ushort4 u; } H;
        #pragma unroll
        for (int j = 0; j < 4; ++j) H.f[j] = (_Float16)vv[j];
        o[i] = H.u;
    }
}

#define GLOAD(src_, dst_) \
    __builtin_amdgcn_global_load_lds((const AS1 void*)(src_), (AS3 void*)(dst_), 16, 0, 0)

// ------- 256x256 GEMM, BK=32, 4-deep LDS pipeline + 1-deep fragment dbuf -------
// Steady-state body is BRANCHLESS (single basic block) + sched_group_barrier
// 3-reads:8-MFMA interleave; 4-iteration peeled tail keeps R15 semantics.
// MODE 0: f32 out (DOWN)   MODE 1: f16 out (GATE, UP)

#define STAGE4(pA_, pB_, kt_, buf_) do { \
    char* db_ = Lc + (buf_)*32768 + wave*1024; \
    GLOAD((pA_) + aBase + (kt_) + off0, db_); \
    GLOAD((pA_) + aBase + (kt_) + off1, db_ +  8192); \
    GLOAD((pB_) + bBase + (kt_) + off2, db_ + 16384); \
    GLOAD((pB_) + bBase + (kt_) + off3, db_ + 24576); \
  } while (0)

#define RDFRAG(dstA_, dstB_, tt_) do { \
    const char* bp_ = Lc + ((tt_) & 3) * 32768; \
    _Pragma("unroll") \
    for (int m_ = 0; m_ < 8; ++m_) (dstA_)[m_] = *(const f16x8*)(bp_ + pa + m_ * 1024); \
    _Pragma("unroll") \
    for (int n_ = 0; n_ < 4; ++n_) (dstB_)[n_] = *(const f16x8*)(bp_ + pb + n_ * 1024); \
  } while (0)

// steady-state body: branchless, SGB-interleaved
#define BODY_M(t_, curA_, curB_, nxtA_, nxtB_) do { \
    asm volatile("s_waitcnt vmcnt(4)" ::: "memory"); \
    BARR; \
    STAGE4(A0, B0, ((t_) + 3) << 5, ((t_) + 3) & 3); \
    RDFRAG(nxtA_, nxtB_, (t_) + 1); \
    _Pragma("unroll") \
    for (int m_ = 0; m_ < 8; ++m_) \
      _Pragma("unroll") \
      for (int n_ = 0; n_ < 4; ++n_) \
        acc[m_][n_] = __builtin_amdgcn_mfma_f32_16x16x32_f16((curA_)[m_], (curB_)[n_], acc[m_][n_], 0, 0, 0); \
    __builtin_amdgcn_sched_group_barrier(0x010, 4, 0); \
    _Pragma("unroll") \
    for (int g_ = 0; g_ < 4; ++g_) { \
      __builtin_amdgcn_sched_group_barrier(0x100, 3, 0); \
      __builtin_amdgcn_sched_group_barrier(0x008, 8, 0); \
    } \
  } while (0)

// tail body: R15 semantics with conditionals
#define BODY_T(t_, curA_, curB_, nxtA_, nxtB_) do { \
    if ((t_) + 2 < NT) asm volatile("s_waitcnt vmcnt(4)" ::: "memory"); \
    else               asm volatile("s_waitcnt vmcnt(0)" ::: "memory"); \
    BARR; \
    if ((t_) + 3 < NT) STAGE4(A0, B0, ((t_) + 3) << 5, ((t_) + 3) & 3); \
    if ((t_) + 1 < NT) RDFRAG(nxtA_, nxtB_, (t_) + 1); \
    __builtin_amdgcn_s_setprio(1); \
    _Pragma("unroll") \
    for (int m_ = 0; m_ < 8; ++m_) \
      _Pragma("unroll") \
      for (int n_ = 0; n_ < 4; ++n_) \
        acc[m_][n_] = __builtin_amdgcn_mfma_f32_16x16x32_f16((curA_)[m_], (curB_)[n_], acc[m_][n_], 0, 0, 0); \
    __builtin_amdgcn_s_setprio(0); \
  } while (0)

template <int MODE>
__global__ __launch_bounds__(512, 2) void gemm4(
    const _Float16* __restrict__ A0, const _Float16* __restrict__ B0,
    int N, int Kp, float* __restrict__ Cf, _Float16* __restrict__ Ch)
{
    __shared__ __align__(128) char Lc[131072];   // 4 bufs x 32 KB (A 16K | B 16K)
    const int tid  = threadIdx.x;
    const int lane = tid & 63;
    const int wave = tid >> 6;
    const int wr = wave >> 2, wc = wave & 3;     // wave tile 128x64

    // XCD-bijective block swizzle
    const int gx = gridDim.x, gy = gridDim.y;
    const int nwg = gx * gy;
    const int orig = blockIdx.y * gx + blockIdx.x;
    const int q = nwg >> 3, r = nwg & 7, xcd = orig & 7, lid = orig >> 3;
    const int wg = (xcd < r ? xcd * (q + 1) : r * (q + 1) + (xcd - r) * q) + lid;
    const int bm = wg / gy, bn = wg % gy;

    // staging map: linear LDS dest (tid*16) <- inverse-swizzled global source
    int off0, off1, off2, off3;
    {
        int o[4];
        #pragma unroll
        for (int g = 0; g < 4; ++g) {
            int p = g * 8192 + tid * 16;
            int l = swzA(p);
            int row = (l >> 6) & 255;
            int col = (l & 63) >> 1;
            o[g] = row * Kp + col;
        }
        off0 = o[0]; off1 = o[1]; off2 = o[2]; off3 = o[3];
    }
    const size_t aBase = (size_t)bm * 256 * Kp;
    const size_t bBase = (size_t)bn * 256 * Kp;

    const int l15 = lane & 15, lhi = lane >> 4;
    const int pa = swzA((wr * 128 + l15) * 64 + lhi * 16);
    const int pb = swzA(16384 + (wc * 64 + l15) * 64 + lhi * 16);

    const int NT = Kp >> 5;                       // 64 or 256 (even, >= 8)
    f32x4 acc[8][4] = {};
    f16x8 a0f[8], b0f[4], a1f[8], b1f[4];

    STAGE4(A0, B0, 0,  0);
    STAGE4(A0, B0, 32, 1);
    STAGE4(A0, B0, 64, 2);
    asm volatile("s_waitcnt vmcnt(8)" ::: "memory");
    BARR;
    RDFRAG(a0f, b0f, 0);

    // main loop: branchless pairs, t .. NT-6
    for (int t = 0; t + 5 < NT; t += 2) {
        BODY_M(t,     a0f, b0f, a1f, b1f);
        BODY_M(t + 1, a1f, b1f, a0f, b0f);
    }
    // peeled tail: t = NT-4 .. NT-1
    for (int t = NT - 4; t < NT; t += 2) {
        BODY_T(t,     a0f, b0f, a1f, b1f);
        BODY_T(t + 1, a1f, b1f, a0f, b0f);
    }

    // epilogue; acc layout: col = lane&15, row = (lane>>4)*4 + reg
    const int r0 = bm * 256 + wr * 128 + (lane >> 4) * 4;
    const int c0 = bn * 256 + wc * 64 + (lane & 15);
    #pragma unroll
    for (int m = 0; m < 8; ++m) {
        #pragma unroll
        for (int n = 0; n < 4; ++n) {
            #pragma unroll
            for (int rr = 0; rr < 4; ++rr) {
                const size_t idx = (size_t)(r0 + m * 16 + rr) * N + (c0 + n * 16);
                if (MODE == 0) Cf[idx] = acc[m][n][rr];
                else           Ch[idx] = (_Float16)acc[m][n][rr];
            }
        }
    }
}

// ---- topk + exact band-recompute + fused P = mask * g * u — VECTORIZED (R15) ----

__global__ __launch_bounds__(256) void topk_sel(
    _Float16* __restrict__ GP, const _Float16* __restrict__ U,
    const float* __restrict__ xf, const float* __restrict__ Wgf)
{
    __shared__ ushort keys[IDIM];
    __shared__ float  xrow[HDIM];
    __shared__ unsigned char bmap[IDIM];
    __shared__ unsigned hist[256], sA_[256], sB_[256];
    __shared__ unsigned selBin, selAbove;
    __shared__ int Acnt, nbv;
    __shared__ int   bidxs[MAXB];
    __shared__ float bval[MAXB];
    __shared__ int   kflag[MAXB];

    const int tid = threadIdx.x;
    const int t = blockIdx.x;
    _Float16* grow = GP + (size_t)t * IDIM;
    const _Float16* urow = U + (size_t)t * IDIM;

    if (tid == 0) { Acnt = 0; nbv = 0; }
    for (int j8 = tid * 8; j8 < IDIM; j8 += 2048) {
        u16x8 v = *(const u16x8*)(grow + j8);
        u16x8 k;
        #pragma unroll
        for (int e = 0; e < 8; ++e) k[e] = (ushort)(v[e] & 0x7FFFu);
        *(u16x8*)(keys + j8) = k;
    }
    for (int j4 = tid; j4 < IDIM / 4; j4 += 256)
        ((unsigned*)bmap)[j4] = 0xFFFFFFFFu;
    for (int j4 = tid * 4; j4 < HDIM; j4 += 1024)
        *(float4*)(xrow + j4) = *(const float4*)(xf + (size_t)t * HDIM + j4);
    __syncthreads();

    unsigned kq = 0;
    int Krem = KKEEP;
    for (int pass = 0; pass < 2; ++pass) {
        const int shift = pass == 0 ? 7 : 0;
        const unsigned msk = pass == 0 ? 255u : 127u;
        hist[tid] = 0;
        __syncthreads();
        for (int j8 = tid * 8; j8 < IDIM; j8 += 2048) {
            u16x8 kv = *(const u16x8*)(keys + j8);
            #pragma unroll
            for (int e = 0; e < 8; ++e) {
                unsigned k = kv[e];
                bool ok = (pass == 0) || ((k >> 7) == (kq >> 7));
                if (ok) atomicAdd(&hist[(k >> shift) & msk], 1u);
            }
        }
        __syncthreads();
        sA_[tid] = hist[tid];
        __syncthreads();
        unsigned *src = sA_, *dst = sB_;
        for (int off = 1; off < 256; off <<= 1) {
            unsigned v = src[tid] + ((tid + off < 256) ? src[tid + off] : 0u);
            dst[tid] = v;
            __syncthreads();
            unsigned* tmp = src; src = dst; dst = tmp;
        }
        unsigned S  = src[tid];
        unsigned Sn = (tid < 255) ? src[tid + 1] : 0u;
        if ((int)S >= Krem && (int)Sn < Krem) { selBin = (unsigned)tid; selAbove = Sn; }
        __syncthreads();
        kq |= selBin << shift;
        Krem -= (int)selAbove;
        __syncthreads();
    }
    H16 cv; cv.u = (ushort)kq;
    const float kthf = (float)cv.h;
    const float hif = kthf + BAND;
    const float lof = kthf - BAND;

    for (int j8 = tid * 8; j8 < IDIM; j8 += 2048) {
        u16x8 kv = *(const u16x8*)(keys + j8);
        #pragma unroll
        for (int e = 0; e < 8; ++e) {
            H16 c; c.u = kv[e];
            float v = (float)c.h;
            if (v > hif) atomicAdd(&Acnt, 1);
            else if (v >= lof) {
                int s = atomicAdd(&nbv, 1);
                if (s < MAXB) { bidxs[s] = j8 + e; bmap[j8 + e] = (unsigned char)s; }
            }
        }
    }
    __syncthreads();

    const int nbc = nbv < MAXB ? nbv : MAXB;
    int R = KKEEP - Acnt;
    R = R < 0 ? 0 : (R > nbc ? nbc : R);

    const int wv = tid >> 6, ln = tid & 63;
    for (int j = wv; j < nbc; j += 4) {
        const float* wrow = Wgf + (size_t)bidxs[j] * HDIM;
        float s = 0.f;
        #pragma unroll
        for (int it = 0; it < HDIM / 256; ++it) {
            const int c = it * 256 + ln * 4;
            float4 w = *(const float4*)(wrow + c);
            float4 xv = *(const float4*)(xrow + c);
            s = fmaf(xv.x, w.x, s);
            s = fmaf(xv.y, w.y, s);
            s = fmaf(xv.z, w.z, s);
            s = fmaf(xv.w, w.w, s);
        }
        #pragma unroll
        for (int o = 32; o; o >>= 1) s += __shfl_xor(s, o);
        if (ln == 0) bval[j] = fabsf(s);
    }
    __syncthreads();

    for (int j = tid; j < nbc; j += 256) {
        int rk = 0;
        float vj = bval[j];
        for (int k = 0; k < nbc; ++k) rk += (bval[k] > vj);
        kflag[j] = (rk < R) ? 1 : 0;
    }
    __syncthreads();

    for (int j8 = tid * 8; j8 < IDIM; j8 += 2048) {
        u16x8 g8 = *(const u16x8*)(grow + j8);
        u16x8 u8 = *(const u16x8*)(urow + j8);
        u16x8 p8;
        #pragma unroll
        for (int e = 0; e < 8; ++e) {
            H16 cg; cg.u = g8[e];
            H16 cu; cu.u = u8[e];
            float g = (float)cg.h;
            float v = fabsf(g);
            bool keep;
            unsigned char s = bmap[j8 + e];
            if (s != 255)      keep = (kflag[s] != 0);
            else if (v > hif)  keep = true;
            else if (v < lof)  keep = false;
            else               keep = (v >= kthf);
            H16 cp; cp.h = keep ? (_Float16)(g * (float)cu.h) : (_Float16)0.f;
            p8[e] = cp.u;
        }
        *(u16x8*)(grow + j8) = p8;
    }
}

// ---------------- host ----------------

extern "C" void kernel_launch(void* const* d_in, const int* in_sizes, int n_in,
                              void* d_out, int out_size, void* d_ws, size_t ws_size,
                              hipStream_t stream) {
    const float* x  = (const float*)d_in[0];   // [T,H]
    const float* Wg = (const float*)d_in[1];   // [I,H]
    const float* Wu = (const float*)d_in[2];   // [I,H]
    const float* Wd = (const float*)d_in[3];   // [H,I]

    const size_t NE   = (size_t)T_TOK * HDIM;
    const size_t szH2 = NE * 2;

    char* ws = (char*)d_ws;
    _Float16* xh   = (_Float16*)ws;
    _Float16* Wgh  = (_Float16*)(ws + szH2);
    _Float16* Wu16 = (_Float16*)(ws + 2 * szH2);
    _Float16* Wd16 = (_Float16*)(ws + 3 * szH2);
    _Float16* G    = (_Float16*)(ws + 4 * szH2);   // [T][I] f16 gate -> P in place
    _Float16* Uc   = (_Float16*)d_out;             // per-chunk U

    const long n4 = (long)(NE / 4);
    cast_f16<<<1024, 256, 0, stream>>>((const float4*)x,  (ushort4*)xh,   n4);
    cast_f16<<<1024, 256, 0, stream>>>((const float4*)Wg, (ushort4*)Wgh,  n4);
    cast_f16<<<1024, 256, 0, stream>>>((const float4*)Wu, (ushort4*)Wu16, n4);
    cast_f16<<<1024, 256, 0, stream>>>((const float4*)Wd, (ushort4*)Wd16, n4);

    // GATE: full-size 1-pass f16 gate
    gemm4<1><<<dim3(T_TOK / 256, IDIM / 256), 512, 0, stream>>>(
        xh, Wgh, IDIM, HDIM, nullptr, G);

    for (int c0 = 0; c0 < T_TOK; c0 += TCHK) {
        gemm4<1><<<dim3(TCHK / 256, IDIM / 256), 512, 0, stream>>>(
            xh + (size_t)c0 * HDIM, Wu16, IDIM, HDIM, nullptr, Uc);
        topk_sel<<<TCHK, 256, 0, stream>>>(
            G + (size_t)c0 * IDIM, Uc, x + (size_t)c0 * HDIM, Wg);
    }

    // DOWN: out = P @ Wd^T
    gemm4<0><<<dim3(T_TOK / 256, HDIM / 256), 512, 0, stream>>>(
        G, Wd16, HDIM, IDIM, (float*)d_out, nullptr);
}

// Round 19
// 1201.854 us; speedup vs baseline: 1.1067x; 1.0196x over previous
//
#include <hip/hip_runtime.h>

#define T_TOK 8192   // B*S tokens
#define HDIM  2048
#define IDIM  8192
#define KKEEP 4096
#define TCHK  4096   // token chunk (U parks in d_out, 67 MB)
#define BAND  1.6e-3f
#define MAXB  192

typedef _Float16 f16x8 __attribute__((ext_vector_type(8)));
typedef float    f32x4 __attribute__((ext_vector_type(4)));
typedef ushort   u16x8 __attribute__((ext_vector_type(8)));

#define AS1 __attribute__((address_space(1)))
#define AS3 __attribute__((address_space(3)))
#define BARR asm volatile("s_barrier" ::: "memory")

// LDS permutation for 64-B rows (BK=32): bits[4:5] ^= bits[7:8], bit[6] ^= bit[8].
__device__ __forceinline__ int swzA(int b) {
    return b ^ ((b >> 3) & 0x30) ^ ((b >> 2) & 0x40);
}

union H16 { ushort u; _Float16 h; };

// ---------------- merged cast (grid.y = array index) ----------------

__global__ void cast_all(const float4* __restrict__ x,  const float4* __restrict__ wg,
                         const float4* __restrict__ wu, const float4* __restrict__ wd,
                         ushort4* __restrict__ xo,  ushort4* __restrict__ wgo,
                         ushort4* __restrict__ wuo, ushort4* __restrict__ wdo, long n4) {
    const float4* in; ushort4* out;
    switch (blockIdx.y) {
        case 0:  in = x;  out = xo;  break;
        case 1:  in = wg; out = wgo; break;
        case 2:  in = wu; out = wuo; break;
        default: in = wd; out = wdo; break;
    }
    long stride = (long)gridDim.x * blockDim.x;
    for (long i = (long)blockIdx.x * blockDim.x + threadIdx.x; i < n4; i += stride) {
        float4 v = in[i];
        float vv[4] = {v.x, v.y, v.z, v.w};
        union { _Float16 f[4]; ushort4 u; } H;
        #pragma unroll
        for (int j = 0; j < 4; ++j) H.f[j] = (_Float16)vv[j];
        out[i] = H.u;
    }
}

#define GLOAD(src_, dst_) \
    __builtin_amdgcn_global_load_lds((const AS1 void*)(src_), (AS3 void*)(dst_), 16, 0, 0)

// ------- 256x256 GEMM core (R18): BK=32, 4-deep LDS pipeline + frag dbuf -------

#define STAGE4(pA_, pB_, kt_, buf_) do { \
    char* db_ = Lc + (buf_)*32768 + wave*1024; \
    GLOAD((pA_) + aBase + (kt_) + off0, db_); \
    GLOAD((pA_) + aBase + (kt_) + off1, db_ +  8192); \
    GLOAD((pB_) + bBase + (kt_) + off2, db_ + 16384); \
    GLOAD((pB_) + bBase + (kt_) + off3, db_ + 24576); \
  } while (0)

#define RDFRAG(dstA_, dstB_, tt_) do { \
    const char* bp_ = Lc + ((tt_) & 3) * 32768; \
    _Pragma("unroll") \
    for (int m_ = 0; m_ < 8; ++m_) (dstA_)[m_] = *(const f16x8*)(bp_ + pa + m_ * 1024); \
    _Pragma("unroll") \
    for (int n_ = 0; n_ < 4; ++n_) (dstB_)[n_] = *(const f16x8*)(bp_ + pb + n_ * 1024); \
  } while (0)

#define BODY_M(pA_, pB_, t_, curA_, curB_, nxtA_, nxtB_) do { \
    asm volatile("s_waitcnt vmcnt(4)" ::: "memory"); \
    BARR; \
    STAGE4(pA_, pB_, ((t_) + 3) << 5, ((t_) + 3) & 3); \
    RDFRAG(nxtA_, nxtB_, (t_) + 1); \
    _Pragma("unroll") \
    for (int m_ = 0; m_ < 8; ++m_) \
      _Pragma("unroll") \
      for (int n_ = 0; n_ < 4; ++n_) \
        acc[m_][n_] = __builtin_amdgcn_mfma_f32_16x16x32_f16((curA_)[m_], (curB_)[n_], acc[m_][n_], 0, 0, 0); \
    __builtin_amdgcn_sched_group_barrier(0x010, 4, 0); \
    _Pragma("unroll") \
    for (int g_ = 0; g_ < 4; ++g_) { \
      __builtin_amdgcn_sched_group_barrier(0x100, 3, 0); \
      __builtin_amdgcn_sched_group_barrier(0x008, 8, 0); \
    } \
  } while (0)

#define BODY_T(pA_, pB_, t_, curA_, curB_, nxtA_, nxtB_) do { \
    if ((t_) + 2 < NT) asm volatile("s_waitcnt vmcnt(4)" ::: "memory"); \
    else               asm volatile("s_waitcnt vmcnt(0)" ::: "memory"); \
    BARR; \
    if ((t_) + 3 < NT) STAGE4(pA_, pB_, ((t_) + 3) << 5, ((t_) + 3) & 3); \
    if ((t_) + 1 < NT) RDFRAG(nxtA_, nxtB_, (t_) + 1); \
    __builtin_amdgcn_s_setprio(1); \
    _Pragma("unroll") \
    for (int m_ = 0; m_ < 8; ++m_) \
      _Pragma("unroll") \
      for (int n_ = 0; n_ < 4; ++n_) \
        acc[m_][n_] = __builtin_amdgcn_mfma_f32_16x16x32_f16((curA_)[m_], (curB_)[n_], acc[m_][n_], 0, 0, 0); \
    __builtin_amdgcn_s_setprio(0); \
  } while (0)

// shared per-block setup (staging offsets, ds_read bases)
#define GEMM_SETUP \
    const int tid  = threadIdx.x; \
    const int lane = tid & 63; \
    const int wave = tid >> 6; \
    const int wr = wave >> 2, wc = wave & 3; \
    int off0, off1, off2, off3; \
    { \
        int o[4]; \
        _Pragma("unroll") \
        for (int g = 0; g < 4; ++g) { \
            int p = g * 8192 + tid * 16; \
            int l = swzA(p); \
            int row = (l >> 6) & 255; \
            int col = (l & 63) >> 1; \
            o[g] = row * Kp + col; \
        } \
        off0 = o[0]; off1 = o[1]; off2 = o[2]; off3 = o[3]; \
    } \
    const int l15 = lane & 15, lhi = lane >> 4; \
    const int pa = swzA((wr * 128 + l15) * 64 + lhi * 16); \
    const int pb = swzA(16384 + (wc * 64 + l15) * 64 + lhi * 16);

#define GEMM_KLOOP(pA_, pB_) \
    STAGE4(pA_, pB_, 0,  0); \
    STAGE4(pA_, pB_, 32, 1); \
    STAGE4(pA_, pB_, 64, 2); \
    asm volatile("s_waitcnt vmcnt(8)" ::: "memory"); \
    BARR; \
    RDFRAG(a0f, b0f, 0); \
    for (int t = 0; t + 5 < NT; t += 2) { \
        BODY_M(pA_, pB_, t,     a0f, b0f, a1f, b1f); \
        BODY_M(pA_, pB_, t + 1, a1f, b1f, a0f, b0f); \
    } \
    for (int t = NT - 4; t < NT; t += 2) { \
        BODY_T(pA_, pB_, t,     a0f, b0f, a1f, b1f); \
        BODY_T(pA_, pB_, t + 1, a1f, b1f, a0f, b0f); \
    }

// ---- gemm4: single-operand (DOWN f32 / generic f16) ----
template <int MODE>
__global__ __launch_bounds__(512, 2) void gemm4(
    const _Float16* __restrict__ A0, const _Float16* __restrict__ B0,
    int N, int Kp, float* __restrict__ Cf, _Float16* __restrict__ Ch)
{
    __shared__ __align__(128) char Lc[131072];
    GEMM_SETUP;

    const int gx = gridDim.x, gy = gridDim.y;
    const int nwg = gx * gy;
    const int orig = blockIdx.y * gx + blockIdx.x;
    const int q = nwg >> 3, r = nwg & 7, xcd = orig & 7, lid = orig >> 3;
    const int wg = (xcd < r ? xcd * (q + 1) : r * (q + 1) + (xcd - r) * q) + lid;
    const int bm = wg / gy, bn = wg % gy;

    const size_t aBase = (size_t)bm * 256 * Kp;
    const size_t bBase = (size_t)bn * 256 * Kp;

    const int NT = Kp >> 5;
    f32x4 acc[8][4] = {};
    f16x8 a0f[8], b0f[4], a1f[8], b1f[4];

    GEMM_KLOOP(A0, B0);

    const int r0 = bm * 256 + wr * 128 + (lane >> 4) * 4;
    const int c0 = bn * 256 + wc * 64 + (lane & 15);
    #pragma unroll
    for (int m = 0; m < 8; ++m)
        #pragma unroll
        for (int n = 0; n < 4; ++n)
            #pragma unroll
            for (int rr = 0; rr < 4; ++rr) {
                const size_t idx = (size_t)(r0 + m * 16 + rr) * N + (c0 + n * 16);
                if (MODE == 0) Cf[idx] = acc[m][n][rr];
                else           Ch[idx] = (_Float16)acc[m][n][rr];
            }
}

// ---- gemm4z: z-merged GATE+UP (same A, B = Wg or Wu, z innermost post-swizzle) ----
__global__ __launch_bounds__(512, 2) void gemm4z(
    const _Float16* __restrict__ A0, const _Float16* __restrict__ Bg,
    const _Float16* __restrict__ Bu, int N, int Kp,
    _Float16* __restrict__ Gout, _Float16* __restrict__ Uout)
{
    __shared__ __align__(128) char Lc[131072];
    GEMM_SETUP;

    // flat grid = 2 * (M/256) * (N/256); XCD-bijective swizzle, then z innermost
    const int nwg = gridDim.x;
    const int orig = blockIdx.x;
    const int q = nwg >> 3, r = nwg & 7, xcd = orig & 7, lid = orig >> 3;
    const int wg = (xcd < r ? xcd * (q + 1) : r * (q + 1) + (xcd - r) * q) + lid;
    const int z = wg & 1;
    const int rest = wg >> 1;
    const int gy = N / 256;
    const int bm = rest / gy, bn = rest % gy;

    const _Float16* B0 = z ? Bu : Bg;
    _Float16* Ch = z ? Uout : Gout;

    const size_t aBase = (size_t)bm * 256 * Kp;
    const size_t bBase = (size_t)bn * 256 * Kp;

    const int NT = Kp >> 5;
    f32x4 acc[8][4] = {};
    f16x8 a0f[8], b0f[4], a1f[8], b1f[4];

    GEMM_KLOOP(A0, B0);

    const int r0 = bm * 256 + wr * 128 + (lane >> 4) * 4;
    const int c0 = bn * 256 + wc * 64 + (lane & 15);
    #pragma unroll
    for (int m = 0; m < 8; ++m)
        #pragma unroll
        for (int n = 0; n < 4; ++n)
            #pragma unroll
            for (int rr = 0; rr < 4; ++rr)
                Ch[(size_t)(r0 + m * 16 + rr) * N + (c0 + n * 16)] = (_Float16)acc[m][n][rr];
}

// ---- topk + exact band-recompute + fused P = mask * g * u — VECTORIZED (R15) ----

__global__ __launch_bounds__(256) void topk_sel(
    _Float16* __restrict__ GP, const _Float16* __restrict__ U,
    const float* __restrict__ xf, const float* __restrict__ Wgf)
{
    __shared__ ushort keys[IDIM];
    __shared__ float  xrow[HDIM];
    __shared__ unsigned char bmap[IDIM];
    __shared__ unsigned hist[256], sA_[256], sB_[256];
    __shared__ unsigned selBin, selAbove;
    __shared__ int Acnt, nbv;
    __shared__ int   bidxs[MAXB];
    __shared__ float bval[MAXB];
    __shared__ int   kflag[MAXB];

    const int tid = threadIdx.x;
    const int t = blockIdx.x;
    _Float16* grow = GP + (size_t)t * IDIM;
    const _Float16* urow = U + (size_t)t * IDIM;

    if (tid == 0) { Acnt = 0; nbv = 0; }
    for (int j8 = tid * 8; j8 < IDIM; j8 += 2048) {
        u16x8 v = *(const u16x8*)(grow + j8);
        u16x8 k;
        #pragma unroll
        for (int e = 0; e < 8; ++e) k[e] = (ushort)(v[e] & 0x7FFFu);
        *(u16x8*)(keys + j8) = k;
    }
    for (int j4 = tid; j4 < IDIM / 4; j4 += 256)
        ((unsigned*)bmap)[j4] = 0xFFFFFFFFu;
    for (int j4 = tid * 4; j4 < HDIM; j4 += 1024)
        *(float4*)(xrow + j4) = *(const float4*)(xf + (size_t)t * HDIM + j4);
    __syncthreads();

    unsigned kq = 0;
    int Krem = KKEEP;
    for (int pass = 0; pass < 2; ++pass) {
        const int shift = pass == 0 ? 7 : 0;
        const unsigned msk = pass == 0 ? 255u : 127u;
        hist[tid] = 0;
        __syncthreads();
        for (int j8 = tid * 8; j8 < IDIM; j8 += 2048) {
            u16x8 kv = *(const u16x8*)(keys + j8);
            #pragma unroll
            for (int e = 0; e < 8; ++e) {
                unsigned k = kv[e];
                bool ok = (pass == 0) || ((k >> 7) == (kq >> 7));
                if (ok) atomicAdd(&hist[(k >> shift) & msk], 1u);
            }
        }
        __syncthreads();
        sA_[tid] = hist[tid];
        __syncthreads();
        unsigned *src = sA_, *dst = sB_;
        for (int off = 1; off < 256; off <<= 1) {
            unsigned v = src[tid] + ((tid + off < 256) ? src[tid + off] : 0u);
            dst[tid] = v;
            __syncthreads();
            unsigned* tmp = src; src = dst; dst = tmp;
        }
        unsigned S  = src[tid];
        unsigned Sn = (tid < 255) ? src[tid + 1] : 0u;
        if ((int)S >= Krem && (int)Sn < Krem) { selBin = (unsigned)tid; selAbove = Sn; }
        __syncthreads();
        kq |= selBin << shift;
        Krem -= (int)selAbove;
        __syncthreads();
    }
    H16 cv; cv.u = (ushort)kq;
    const float kthf = (float)cv.h;
    const float hif = kthf + BAND;
    const float lof = kthf - BAND;

    for (int j8 = tid * 8; j8 < IDIM; j8 += 2048) {
        u16x8 kv = *(const u16x8*)(keys + j8);
        #pragma unroll
        for (int e = 0; e < 8; ++e) {
            H16 c; c.u = kv[e];
            float v = (float)c.h;
            if (v > hif) atomicAdd(&Acnt, 1);
            else if (v >= lof) {
                int s = atomicAdd(&nbv, 1);
                if (s < MAXB) { bidxs[s] = j8 + e; bmap[j8 + e] = (unsigned char)s; }
            }
        }
    }
    __syncthreads();

    const int nbc = nbv < MAXB ? nbv : MAXB;
    int R = KKEEP - Acnt;
    R = R < 0 ? 0 : (R > nbc ? nbc : R);

    const int wv = tid >> 6, ln = tid & 63;
    for (int j = wv; j < nbc; j += 4) {
        const float* wrow = Wgf + (size_t)bidxs[j] * HDIM;
        float s = 0.f;
        #pragma unroll
        for (int it = 0; it < HDIM / 256; ++it) {
            const int c = it * 256 + ln * 4;
            float4 w = *(const float4*)(wrow + c);
            float4 xv = *(const float4*)(xrow + c);
            s = fmaf(xv.x, w.x, s);
            s = fmaf(xv.y, w.y, s);
            s = fmaf(xv.z, w.z, s);
            s = fmaf(xv.w, w.w, s);
        }
        #pragma unroll
        for (int o = 32; o; o >>= 1) s += __shfl_xor(s, o);
        if (ln == 0) bval[j] = fabsf(s);
    }
    __syncthreads();

    for (int j = tid; j < nbc; j += 256) {
        int rk = 0;
        float vj = bval[j];
        for (int k = 0; k < nbc; ++k) rk += (bval[k] > vj);
        kflag[j] = (rk < R) ? 1 : 0;
    }
    __syncthreads();

    for (int j8 = tid * 8; j8 < IDIM; j8 += 2048) {
        u16x8 g8 = *(const u16x8*)(grow + j8);
        u16x8 u8 = *(const u16x8*)(urow + j8);
        u16x8 p8;
        #pragma unroll
        for (int e = 0; e < 8; ++e) {
            H16 cg; cg.u = g8[e];
            H16 cu; cu.u = u8[e];
            float g = (float)cg.h;
            float v = fabsf(g);
            bool keep;
            unsigned char s = bmap[j8 + e];
            if (s != 255)      keep = (kflag[s] != 0);
            else if (v > hif)  keep = true;
            else if (v < lof)  keep = false;
            else               keep = (v >= kthf);
            H16 cp; cp.h = keep ? (_Float16)(g * (float)cu.h) : (_Float16)0.f;
            p8[e] = cp.u;
        }
        *(u16x8*)(grow + j8) = p8;
    }
}

// ---------------- host ----------------

extern "C" void kernel_launch(void* const* d_in, const int* in_sizes, int n_in,
                              void* d_out, int out_size, void* d_ws, size_t ws_size,
                              hipStream_t stream) {
    const float* x  = (const float*)d_in[0];   // [T,H]
    const float* Wg = (const float*)d_in[1];   // [I,H]
    const float* Wu = (const float*)d_in[2];   // [I,H]
    const float* Wd = (const float*)d_in[3];   // [H,I]

    const size_t NE   = (size_t)T_TOK * HDIM;
    const size_t szH2 = NE * 2;

    char* ws = (char*)d_ws;
    _Float16* xh   = (_Float16*)ws;
    _Float16* Wgh  = (_Float16*)(ws + szH2);
    _Float16* Wu16 = (_Float16*)(ws + 2 * szH2);
    _Float16* Wd16 = (_Float16*)(ws + 3 * szH2);
    _Float16* G    = (_Float16*)(ws + 4 * szH2);   // [T][I] f16 gate -> P in place
    _Float16* Uc   = (_Float16*)d_out;             // per-chunk U

    const long n4 = (long)(NE / 4);
    cast_all<<<dim3(512, 4), 256, 0, stream>>>(
        (const float4*)x, (const float4*)Wg, (const float4*)Wu, (const float4*)Wd,
        (ushort4*)xh, (ushort4*)Wgh, (ushort4*)Wu16, (ushort4*)Wd16, n4);

    // per chunk: z-merged GATE+UP (shared A panels), then selection + P in place
    for (int c0 = 0; c0 < T_TOK; c0 += TCHK) {
        const int nwg = 2 * (TCHK / 256) * (IDIM / 256);   // 1024, %8==0
        gemm4z<<<dim3(nwg), 512, 0, stream>>>(
            xh + (size_t)c0 * HDIM, Wgh, Wu16, IDIM, HDIM,
            G + (size_t)c0 * IDIM, Uc);
        topk_sel<<<TCHK, 256, 0, stream>>>(
            G + (size_t)c0 * IDIM, Uc, x + (size_t)c0 * HDIM, Wg);
    }

    // DOWN: out = P @ Wd^T
    gemm4<0><<<dim3(T_TOK / 256, HDIM / 256), 512, 0, stream>>>(
        G, Wd16, HDIM, IDIM, (float*)d_out, nullptr);
}